// Round 4
// baseline (942.535 us; speedup 1.0000x reference)
//
#include <hip/hip_runtime.h>

#define BT 4096
#define H  2048
#define V  32000
#define BM 256
#define BN 256
#define BKB 128                   /* fp8 bytes per K-tile row */
#define KT (H / BKB)              /* 16 K-tiles */
#define NTILES (V / BN)           /* 125 */
#define MTILES (BT / BM)          /* 16 */
#define NWG (MTILES * NTILES)     /* 2000, % 8 == 0 -> bijective XCD swizzle */
#define IGNORE_INDEX (-100)

typedef int   v8i   __attribute__((ext_vector_type(8)));
typedef float f32x4 __attribute__((ext_vector_type(4)));

#define SCALE_ONE 0x7F7F7F7F        /* E8M0 127 = 2^0 in every byte */
#define UNSCALE   (1.0f / 65536.0f) /* inputs pre-scaled by 2^8 each */

#define BAR()   __builtin_amdgcn_s_barrier()
#define LGKM0() asm volatile("s_waitcnt lgkmcnt(0)" ::: "memory")

// ------------------------------------------- fp32 -> fp8 e4m3, FRAG-PACKED
// Coalesced version: wave-local LDS transpose. Per task (row-group g, K-tile
// kt): stage 16 rows x 128 floats coalesced (1KB/instr), then each lane
// gathers its 32 floats from LDS and writes the packed 2KB block:
//   byte [c*1024 + lane*16 + b] = fp8( in[g*16 + (lane&15)]
//                                       [kt*128 + (lane>>4)*32 + c*16 + b] )
__global__ __launch_bounds__(256)
void cvt_pack_kernel(const float* __restrict__ in, unsigned char* __restrict__ out,
                     int tasks) {
  __shared__ float ld[4][16][132];           // +4 pad breaks row-bank alias
  const int wv = threadIdx.x >> 6, lane = threadIdx.x & 63;
  const int task = blockIdx.x * 4 + wv;
  if (task >= tasks) return;                 // wave-divergent ok: no block bar
  const int g = task >> 4, kt = task & 15;   // KT = 16
  const float* src = in + (size_t)(g * 16) * H + kt * 128;
#pragma unroll
  for (int i = 0; i < 8; ++i) {              // 512 float4, coalesced
    int idx = i * 64 + lane;
    int r = idx >> 5, c = idx & 31;
    float4 v = *(const float4*)(src + (size_t)r * H + c * 4);
    *(float4*)&ld[wv][r][c * 4] = v;
  }
  LGKM0();                                   // cross-lane LDS visibility
  const int row = lane & 15, kb = (lane >> 4) * 32;
  int p[8];
#pragma unroll
  for (int u = 0; u < 8; ++u) {
    float4 x = *(const float4*)&ld[wv][row][kb + u * 4];
    int v = 0;
    v = __builtin_amdgcn_cvt_pk_fp8_f32(x.x * 256.f, x.y * 256.f, v, false);
    v = __builtin_amdgcn_cvt_pk_fp8_f32(x.z * 256.f, x.w * 256.f, v, true);
    p[u] = v;
  }
  unsigned char* dst = out + ((size_t)g * KT + kt) * 2048 + lane * 16;
  int4 lo; lo.x = p[0]; lo.y = p[1]; lo.z = p[2]; lo.w = p[3];
  int4 hi; hi.x = p[4]; hi.y = p[5]; hi.z = p[6]; hi.w = p[7];
  *(int4*)dst          = lo;                 // plane c=0
  *(int4*)(dst + 1024) = hi;                 // plane c=1
}

// --------------------------------------------------------------------------
// 256x256-tile, 8-wave (2x4), MX-fp8 16x16x128 MFMA.
//
// R3 post-mortem: LDS-port-bound (A-frag reads duplicated 4x across waves).
// v4: A-fragments load DIRECTLY global->VGPR (packed layout = contiguous
// 1KB/instr; A-panel 512KB is L2-resident under nt-fastest ordering, wave
// re-reads hit L1). Only B goes through LDS (2x dup): LDS traffic/K-tile
// drops 288KB -> 160KB, under the ~85-128 B/cy port.
// All loads are register-tracked -> compiler emits exact waitcnts; the loop
// needs ONE barrier per K-tile and no manual vmcnt.
// Pipeline (per kt, 4 logical phases):
//   ph0: ds_read b0-1            ; MFMA a0-3 x b0-1
//   ph1: ds_read b2-3            ; MFMA a0-3 x b2-3
//   ph2: issue A03(kt+1); ds_write B(kt+1)->buf^1; ds_read b0-1
//                                ; MFMA a4-7 x b0-1
//   ph3: ds_read b2-3            ; MFMA a4-7 x b2-3 ; issue A47(kt+1);
//        issue B(kt+2)->regs     ; lgkm0 ; barrier
// Race ledger: buf[kt&1] read during kt, written during kt+1 (ph2) -- all
// kt-reads drained by each wave's lgkm0 before the kt-end barrier. buf^1
// written ph2(kt) was last read in kt-1, before that barrier.
// --------------------------------------------------------------------------
union frag_u { v8i v; int4 h[2]; };

#define MF(C, A, B)                                                         \
  (C) = __builtin_amdgcn_mfma_scale_f32_16x16x128_f8f6f4(                   \
      (A).v, (B).v, (C), 0, 0, 0, SCALE_ONE, 0, SCALE_ONE)

__global__ __launch_bounds__(512, 2)
void gemm_lse_kernel(const unsigned char* __restrict__ Af8,
                     const unsigned char* __restrict__ Bf8,
                     const int* __restrict__ tgt,
                     float* __restrict__ pm, float* __restrict__ pl,
                     float* __restrict__ tl) {
  __shared__ __align__(16) unsigned char Bs[2 * 32768];  // 64 KB (B only)
  __shared__ float red_m[4][BM];
  __shared__ float red_l[4][BM];
  __shared__ int   stgt[BM];

  // T1 bijective XCD swizzle; nt fastest -> consecutive blocks share the
  // 512KB A-panel (L2-resident per XCD); B streams from L3 (65MB cached).
  const int wgid = ((int)blockIdx.x & 7) * (NWG / 8) + ((int)blockIdx.x >> 3);
  const int mt = wgid / NTILES;
  const int nt = wgid % NTILES;
  const int m0 = mt * BM;
  const int n0 = nt * BN;

  const int tid  = threadIdx.x;
  const int lane = tid & 63;
  const int w    = tid >> 6;   // wave 0..7
  const int wr   = w >> 2;     // 0..1 : rows [wr*128, +128)
  const int wc   = w & 3;      // 0..3 : cols [wc*64, +64)
  const int lm   = lane & 15;
  const int q    = lane >> 4;

  if (tid < BM) stgt[tid] = tgt[m0 + tid];
  __syncthreads();

  // A frags: wave's row-groups = m0/16 + wr*8 + i (i=0..7), frag-contiguous.
  const unsigned char* aSrc =
      Af8 + ((size_t)(m0 / 16 + wr * 8) * KT) * 2048 + lane * 16;
  // B staging: wave w loads row-groups {2w, 2w+1} of the B tile.
  const unsigned char* bSrc =
      Bf8 + ((size_t)(n0 / 16 + 2 * w) * KT) * 2048 + lane * 16;

  frag_u a03[4], a47[4];
  int4 bst[4];

  auto loadA = [&](frag_u* f, int kt2, int half) {
    int k = kt2 < KT ? kt2 : KT - 1;
    const unsigned char* p = aSrc + ((size_t)(half * 4) * KT + k) * 2048;
#pragma unroll
    for (int i = 0; i < 4; ++i) {
      f[i].h[0] = *(const int4*)(p + (size_t)i * KT * 2048);
      f[i].h[1] = *(const int4*)(p + (size_t)i * KT * 2048 + 1024);
    }
  };
  auto bload = [&](int kt2) {
    int k = kt2 < KT ? kt2 : KT - 1;
    bst[0] = *(const int4*)(bSrc + (size_t)k * 2048);
    bst[1] = *(const int4*)(bSrc + (size_t)k * 2048 + 1024);
    bst[2] = *(const int4*)(bSrc + ((size_t)KT + k) * 2048);
    bst[3] = *(const int4*)(bSrc + ((size_t)KT + k) * 2048 + 1024);
  };
  auto bwrite = [&](int buf) {
    unsigned char* d = Bs + buf * 32768 + (2 * w) * 2048 + lane * 16;
    *(int4*)(d)        = bst[0];
    *(int4*)(d + 1024) = bst[1];
    *(int4*)(d + 2048) = bst[2];
    *(int4*)(d + 3072) = bst[3];
  };
  auto ldsB = [&](frag_u& f, int buf, int j) {
    const unsigned char* p = Bs + buf * 32768 + (wc * 4 + j) * 2048 + lane * 16;
    f.h[0] = *(const int4*)(p);
    f.h[1] = *(const int4*)(p + 1024);
  };

  f32x4 acc[8][4];
#pragma unroll
  for (int a = 0; a < 8; ++a)
#pragma unroll
    for (int b = 0; b < 4; ++b) acc[a][b] = (f32x4){0.f, 0.f, 0.f, 0.f};

  // ---- prologue
  bload(0);
  loadA(a03, 0, 0);
  loadA(a47, 0, 1);
  bwrite(0);                 // compiler waits bst(0)
  LGKM0();
  BAR();
  bload(1);

#pragma unroll 2
  for (int kt = 0; kt < KT; ++kt) {
    const int buf = kt & 1;
    frag_u fbA, fbB;

    // ---- ph0: a0-3 x b0-1
    ldsB(fbA, buf, 0); ldsB(fbB, buf, 1);
    __builtin_amdgcn_s_setprio(1);
    MF(acc[0][0], a03[0], fbA); MF(acc[1][0], a03[1], fbA);
    MF(acc[2][0], a03[2], fbA); MF(acc[3][0], a03[3], fbA);
    MF(acc[0][1], a03[0], fbB); MF(acc[1][1], a03[1], fbB);
    MF(acc[2][1], a03[2], fbB); MF(acc[3][1], a03[3], fbB);
    __builtin_amdgcn_s_setprio(0);

    // ---- ph1: a0-3 x b2-3
    ldsB(fbA, buf, 2); ldsB(fbB, buf, 3);
    __builtin_amdgcn_s_setprio(1);
    MF(acc[0][2], a03[0], fbA); MF(acc[1][2], a03[1], fbA);
    MF(acc[2][2], a03[2], fbA); MF(acc[3][2], a03[3], fbA);
    MF(acc[0][3], a03[0], fbB); MF(acc[1][3], a03[1], fbB);
    MF(acc[2][3], a03[2], fbB); MF(acc[3][3], a03[3], fbB);
    __builtin_amdgcn_s_setprio(0);

    // ---- ph2: a4-7 x b0-1  (+ issue next A03, commit next B tile to LDS)
    loadA(a03, kt + 1, 0);
    bwrite(buf ^ 1);           // compiler waits bst(kt+1)
    ldsB(fbA, buf, 0); ldsB(fbB, buf, 1);
    __builtin_amdgcn_s_setprio(1);
    MF(acc[4][0], a47[0], fbA); MF(acc[5][0], a47[1], fbA);
    MF(acc[6][0], a47[2], fbA); MF(acc[7][0], a47[3], fbA);
    MF(acc[4][1], a47[0], fbB); MF(acc[5][1], a47[1], fbB);
    MF(acc[6][1], a47[2], fbB); MF(acc[7][1], a47[3], fbB);
    __builtin_amdgcn_s_setprio(0);

    // ---- ph3: a4-7 x b2-3  (+ issue next A47, next-next B -> regs)
    ldsB(fbA, buf, 2); ldsB(fbB, buf, 3);
    __builtin_amdgcn_s_setprio(1);
    MF(acc[4][2], a47[0], fbA); MF(acc[5][2], a47[1], fbA);
    MF(acc[6][2], a47[2], fbA); MF(acc[7][2], a47[3], fbA);
    MF(acc[4][3], a47[0], fbB); MF(acc[5][3], a47[1], fbB);
    MF(acc[6][3], a47[2], fbB); MF(acc[7][3], a47[3], fbB);
    __builtin_amdgcn_s_setprio(0);
    loadA(a47, kt + 1, 1);
    bload(kt + 2);
    LGKM0();                   // own ds_reads + ds_writes drained
    BAR();                     // buf may be overwritten next kt
  }

  __syncthreads();

  // ---- target-logit extraction (C layout: col=lane&15, row=q*4+reg)
#pragma unroll
  for (int ai = 0; ai < 8; ++ai) {
#pragma unroll
    for (int r = 0; r < 4; ++r) {
      int row_local = wr * 128 + ai * 16 + q * 4 + r;
      int c = stgt[row_local] - n0 - wc * 64;
      if ((unsigned)c < 64u && (c & 15) == lm) {
        int bj = c >> 4;
        float v = bj == 0 ? acc[ai][0][r]
                : bj == 1 ? acc[ai][1][r]
                : bj == 2 ? acc[ai][2][r]
                :           acc[ai][3][r];
        tl[m0 + row_local] = v * UNSCALE;
      }
    }
  }

  // ---- per-row (max, sumexp) over this wave's 64 columns
#pragma unroll
  for (int ai = 0; ai < 8; ++ai) {
#pragma unroll
    for (int r = 0; r < 4; ++r) {
      float v0 = acc[ai][0][r] * UNSCALE;
      float v1 = acc[ai][1][r] * UNSCALE;
      float v2 = acc[ai][2][r] * UNSCALE;
      float v3 = acc[ai][3][r] * UNSCALE;
      float mx = fmaxf(fmaxf(v0, v1), fmaxf(v2, v3));
#pragma unroll
      for (int off = 1; off < 16; off <<= 1) mx = fmaxf(mx, __shfl_xor(mx, off));
      float s = __expf(v0 - mx) + __expf(v1 - mx) + __expf(v2 - mx) + __expf(v3 - mx);
#pragma unroll
      for (int off = 1; off < 16; off <<= 1) s += __shfl_xor(s, off);
      if (lm == 0) {
        int row_local = wr * 128 + ai * 16 + q * 4 + r;
        red_m[wc][row_local] = mx;
        red_l[wc][row_local] = s;
      }
    }
  }
  __syncthreads();
  if (tid < BM) {
    float M = fmaxf(fmaxf(red_m[0][tid], red_m[1][tid]),
                    fmaxf(red_m[2][tid], red_m[3][tid]));
    float L = red_l[0][tid] * __expf(red_m[0][tid] - M)
            + red_l[1][tid] * __expf(red_m[1][tid] - M)
            + red_l[2][tid] * __expf(red_m[2][tid] - M)
            + red_l[3][tid] * __expf(red_m[3][tid] - M);
    long idx = (long)nt * BT + (m0 + tid);
    pm[idx] = M;
    pl[idx] = L;
  }
}

// -------------------------------------------- combine partials, wave per row
__global__ __launch_bounds__(256)
void row_lse_kernel(const float* __restrict__ pm, const float* __restrict__ pl,
                    const float* __restrict__ tl, const int* __restrict__ tgt,
                    float* __restrict__ rl) {
  int row  = blockIdx.x * 4 + (threadIdx.x >> 6);
  int lane = threadIdx.x & 63;
  float M = -__builtin_inff();
  float L = 0.f;
  for (int t = lane; t < NTILES; t += 64) {
    float m2 = pm[(long)t * BT + row];
    float l2 = pl[(long)t * BT + row];
    float Mn = fmaxf(M, m2);
    L = L * __expf(M - Mn) + l2 * __expf(m2 - Mn);
    M = Mn;
  }
#pragma unroll
  for (int off = 1; off < 64; off <<= 1) {
    float m2 = __shfl_xor(M, off);
    float l2 = __shfl_xor(L, off);
    float Mn = fmaxf(M, m2);
    L = L * __expf(M - Mn) + l2 * __expf(m2 - Mn);
    M = Mn;
  }
  if (lane == 0) {
    float lse = M + logf(L);
    int t = tgt[row];
    rl[row] = (t != IGNORE_INDEX) ? (lse - tl[row]) : 0.f;
  }
}

// ------------------------------------------------------------- final reduce
__global__ __launch_bounds__(256)
void final_kernel(const float* __restrict__ rl, const int* __restrict__ tgt,
                  float* __restrict__ out) {
  __shared__ float ss[4];
  __shared__ float sc[4];
  float s = 0.f, c = 0.f;
  for (int r = threadIdx.x; r < BT; r += 256) {
    s += rl[r];
    c += (tgt[r] != IGNORE_INDEX) ? 1.f : 0.f;
  }
#pragma unroll
  for (int off = 32; off > 0; off >>= 1) {
    s += __shfl_xor(s, off);
    c += __shfl_xor(c, off);
  }
  int w = threadIdx.x >> 6;
  if ((threadIdx.x & 63) == 0) { ss[w] = s; sc[w] = c; }
  __syncthreads();
  if (threadIdx.x == 0) {
    float S = ss[0] + ss[1] + ss[2] + ss[3];
    float C = sc[0] + sc[1] + sc[2] + sc[3];
    out[0] = S / fmaxf(C, 1.f);
  }
}

extern "C" void kernel_launch(void* const* d_in, const int* in_sizes, int n_in,
                              void* d_out, int out_size, void* d_ws, size_t ws_size,
                              hipStream_t stream) {
  const float* hs  = (const float*)d_in[0];   // hidden_states [BT][H] fp32
  const float* wt  = (const float*)d_in[1];   // weight [V][H] fp32
  const int*   tgt = (const int*)d_in[2];     // targets [BT]
  float*       out = (float*)d_out;

  char* ws = (char*)d_ws;
  size_t off = 0;
  auto alloc = [&](size_t bytes) -> void* {
    void* p = ws + off;
    off += (bytes + 255) & ~(size_t)255;
    return p;
  };
  unsigned char* wf8 = (unsigned char*)alloc((size_t)V * H);        // 65.5 MB packed
  unsigned char* hf8 = (unsigned char*)alloc((size_t)BT * H);       // 8.4 MB packed
  float* pm = (float*)alloc((size_t)NTILES * BT * 4);               // 2.0 MB
  float* pl = (float*)alloc((size_t)NTILES * BT * 4);               // 2.0 MB
  float* tl = (float*)alloc((size_t)BT * 4);
  float* rl = (float*)alloc((size_t)BT * 4);
  (void)ws_size; (void)in_sizes; (void)n_in; (void)out_size;

  // pack tasks: one wave per (16-row group, K-tile)
  cvt_pack_kernel<<<(V / 16) * KT / 4, 256, 0, stream>>>(wt, wf8, (V / 16) * KT);
  cvt_pack_kernel<<<(BT / 16) * KT / 4, 256, 0, stream>>>(hs, hf8, (BT / 16) * KT);

  gemm_lse_kernel<<<NWG, 512, 0, stream>>>(hf8, wf8, tgt, pm, pl, tl);

  row_lse_kernel<<<BT / 4, 256, 0, stream>>>(pm, pl, tl, tgt, rl);
  final_kernel<<<1, 256, 0, stream>>>(rl, tgt, out);
}

// Round 5
// 724.044 us; speedup vs baseline: 1.3018x; 1.3018x over previous
//
#include <hip/hip_runtime.h>

#define BT 4096
#define H  2048
#define V  32000
#define BM 256
#define BN 256
#define BKB 128                   /* fp8 bytes per K-tile row */
#define KT (H / BKB)              /* 16 K-tiles */
#define NTILES (V / BN)           /* 125 */
#define MTILES (BT / BM)          /* 16 */
#define NWG (MTILES * NTILES)     /* 2000, % 8 == 0 -> bijective XCD swizzle */
#define IGNORE_INDEX (-100)

typedef int   v8i   __attribute__((ext_vector_type(8)));
typedef float f32x4 __attribute__((ext_vector_type(4)));

#define SCALE_ONE 0x7F7F7F7F        /* E8M0 127 = 2^0 in every byte */
#define UNSCALE   (1.0f / 65536.0f) /* inputs pre-scaled by 2^8 each */

#define BAR()   __builtin_amdgcn_s_barrier()
#define SB0()   __builtin_amdgcn_sched_barrier(0)
#define LGKM0() asm volatile("s_waitcnt lgkmcnt(0)" ::: "memory")
#define VMC(N)  asm volatile("s_waitcnt vmcnt(" #N ")" ::: "memory")

__device__ inline void load_lds16(const void* g, void* l) {
  __builtin_amdgcn_global_load_lds(
      (const __attribute__((address_space(1))) unsigned int*)g,
      (__attribute__((address_space(3))) unsigned int*)l,
      16, 0, 0);
}

// ------------------------------------------- fp32 -> fp8 e4m3, FRAG-PACKED
// Coalesced: wave-local LDS transpose. Per task (row-group g, K-tile kt):
// stage 16 rows x 128 floats coalesced, then each lane gathers its 32 floats
// from LDS and writes the packed 2KB block:
//   byte [c*1024 + lane*16 + b] = fp8( in[g*16 + (lane&15)]
//                                       [kt*128 + (lane>>4)*32 + c*16 + b] )
__global__ __launch_bounds__(256)
void cvt_pack_kernel(const float* __restrict__ in, unsigned char* __restrict__ out,
                     int tasks) {
  __shared__ float ld[4][16][132];           // +4 pad breaks row-bank alias
  const int wv = threadIdx.x >> 6, lane = threadIdx.x & 63;
  const int task = blockIdx.x * 4 + wv;
  if (task >= tasks) return;                 // wave-divergent ok: no block bar
  const int g = task >> 4, kt = task & 15;   // KT = 16
  const float* src = in + (size_t)(g * 16) * H + kt * 128;
#pragma unroll
  for (int i = 0; i < 8; ++i) {              // 512 float4, coalesced
    int idx = i * 64 + lane;
    int r = idx >> 5, c = idx & 31;
    float4 v = *(const float4*)(src + (size_t)r * H + c * 4);
    *(float4*)&ld[wv][r][c * 4] = v;
  }
  LGKM0();                                   // cross-lane LDS visibility
  const int row = lane & 15, kb = (lane >> 4) * 32;
  int p[8];
#pragma unroll
  for (int u = 0; u < 8; ++u) {
    float4 x = *(const float4*)&ld[wv][row][kb + u * 4];
    int v = 0;
    v = __builtin_amdgcn_cvt_pk_fp8_f32(x.x * 256.f, x.y * 256.f, v, false);
    v = __builtin_amdgcn_cvt_pk_fp8_f32(x.z * 256.f, x.w * 256.f, v, true);
    p[u] = v;
  }
  unsigned char* dst = out + ((size_t)g * KT + kt) * 2048 + lane * 16;
  int4 lo; lo.x = p[0]; lo.y = p[1]; lo.z = p[2]; lo.w = p[3];
  int4 hi; hi.x = p[4]; hi.y = p[5]; hi.z = p[6]; hi.w = p[7];
  *(int4*)dst          = lo;                 // plane c=0
  *(int4*)(dst + 1024) = hi;                 // plane c=1
}

// --------------------------------------------------------------------------
// 256x256-tile, 8-wave (2x4), MX-fp8 16x16x128 MFMA.
// Memory plan = R3 (proven: FETCH 8.9MB, 0 conflicts): packed operands,
// contiguous-1KB global_load_lds staging, linear frag-contiguous LDS,
// frag read = base + lane*16 (+1024).
// Sync plan = NEW: 4 fat phases per 2 K-tiles, ONE barrier per phase
// (R3 had 16 barriers/2kt; sync lockstep was the measured bottleneck).
//   P0: read buf0 a0-3,b0-3   | stage buf1.A(t1)    | 16 MFMA | bar
//   P1: read buf0 a4-7        | stage buf0.B(t0+2)  | 16 MFMA | VMC(4) bar
//   P2: read buf1 a0-3,b0-3   | stage buf0.A(t0+2)  | 16 MFMA | bar
//   P3: read buf1 a4-7        | stage buf1.B(t1+2)  | 16 MFMA | VMC(4) bar
// Hazards: stage->read covered by VMC+bar (buf1 complete at P1-end, buf0 at
// P3-end); read->overwrite covered by compiler lgkm-wait before MFMA (pre-
// barrier) + overwrite issued post-barrier. Last iter: VMC(0) (fewer loads
// in flight, VMC(4) would not drain the needed ones). sched_barrier(0)
// fences stop reg-only chains floating across phase boundaries.
// --------------------------------------------------------------------------
union frag_u { v8i v; int4 h[2]; };

#define MF(C, A, B)                                                         \
  (C) = __builtin_amdgcn_mfma_scale_f32_16x16x128_f8f6f4(                   \
      (A).v, (B).v, (C), 0, 0, 0, SCALE_ONE, 0, SCALE_ONE)

__global__ __launch_bounds__(512, 2)
void gemm_lse_kernel(const unsigned char* __restrict__ Af8,
                     const unsigned char* __restrict__ Bf8,
                     const int* __restrict__ tgt,
                     float* __restrict__ pm, float* __restrict__ pl,
                     float* __restrict__ tl) {
  __shared__ __align__(16) unsigned char As[2 * 32768];  // 64 KB
  __shared__ __align__(16) unsigned char Bs[2 * 32768];  // 64 KB
  __shared__ float red_m[4][BM];
  __shared__ float red_l[4][BM];
  __shared__ int   stgt[BM];

  // T1 bijective XCD swizzle (2000 % 8 == 0), mt fastest within an XCD:
  // 16 consecutive blocks share one 512KB B-panel (L2-resident); A via L3.
  const int wgid = ((int)blockIdx.x & 7) * (NWG / 8) + ((int)blockIdx.x >> 3);
  const int mt = wgid & (MTILES - 1);
  const int nt = wgid / MTILES;
  const int m0 = mt * BM;
  const int n0 = nt * BN;

  const int tid  = threadIdx.x;
  const int lane = tid & 63;
  const int w    = tid >> 6;   // wave 0..7
  const int wr   = w >> 2;     // 0..1 : rows [wr*128, +128)
  const int wc   = w & 3;      // 0..3 : cols [wc*64, +64)
  const int lm   = lane & 15;
  const int q    = lane >> 4;

  if (tid < BM) stgt[tid] = tgt[m0 + tid];
  __syncthreads();  // drains vmcnt before counted staging begins

  // packed source: row-group (m0/16 + hf*8 + w), K-tile kt, 2KB contiguous.
  const unsigned char* aSrc = Af8 + (size_t)(m0 / 16) * KT * 2048;
  const unsigned char* bSrc = Bf8 + (size_t)(n0 / 16) * KT * 2048;

  auto stageA = [&](int buf, int hf, int kt) {
    const unsigned char* s = aSrc + ((size_t)(hf * 8 + w) * KT + kt) * 2048;
    unsigned char* d = As + buf * 32768 + (hf * 8 + w) * 2048;
    load_lds16(s, d);               // plane 0 (contiguous 1KB)
    load_lds16(s + 1024, d + 1024); // plane 1 (contiguous 1KB)
  };
  auto stageB = [&](int buf, int hf, int kt) {
    const unsigned char* s = bSrc + ((size_t)(hf * 8 + w) * KT + kt) * 2048;
    unsigned char* d = Bs + buf * 32768 + (hf * 8 + w) * 2048;
    load_lds16(s, d);
    load_lds16(s + 1024, d + 1024);
  };

  // fragment reads: one per-lane address, immediate offsets only.
  const unsigned char* aRd = As + lane * 16;
  const unsigned char* bRd = Bs + lane * 16;

  auto ldA = [&](frag_u& f, int buf, int i) {
    const unsigned char* p = aRd + buf * 32768 + (wr * 8 + i) * 2048;
    f.h[0] = *(const int4*)(p);
    f.h[1] = *(const int4*)(p + 1024);
  };
  auto ldB = [&](frag_u& f, int buf, int j) {
    const unsigned char* p = bRd + buf * 32768 + (wc * 4 + j) * 2048;
    f.h[0] = *(const int4*)(p);
    f.h[1] = *(const int4*)(p + 1024);
  };

  f32x4 acc[8][4];
#pragma unroll
  for (int a = 0; a < 8; ++a)
#pragma unroll
    for (int b = 0; b < 4; ++b) acc[a][b] = (f32x4){0.f, 0.f, 0.f, 0.f};

  frag_u fa0, fa1, fa2, fa3, fb0, fb1, fb2, fb3;

  // ---- prologue: buf0 fully (8 loads) + buf1.B (4); VMC(4) -> buf0 landed.
  stageA(0, 0, 0); stageA(0, 1, 0); stageB(0, 0, 0); stageB(0, 1, 0);
  stageB(1, 0, 1); stageB(1, 1, 1);
  VMC(4);
  SB0(); BAR(); SB0();

  for (int i = 0; i < 8; ++i) {
    const int t1 = 2 * i + 1;
    const bool pre = (i < 7);

    // ---- P0: buf0, a0-3 x b0-3
    ldA(fa0, 0, 0); ldA(fa1, 0, 1); ldA(fa2, 0, 2); ldA(fa3, 0, 3);
    ldB(fb0, 0, 0); ldB(fb1, 0, 1); ldB(fb2, 0, 2); ldB(fb3, 0, 3);
    stageA(1, 0, t1); stageA(1, 1, t1);
    __builtin_amdgcn_s_setprio(1);
    MF(acc[0][0], fa0, fb0); MF(acc[1][0], fa1, fb0);
    MF(acc[2][0], fa2, fb0); MF(acc[3][0], fa3, fb0);
    MF(acc[0][1], fa0, fb1); MF(acc[1][1], fa1, fb1);
    MF(acc[2][1], fa2, fb1); MF(acc[3][1], fa3, fb1);
    MF(acc[0][2], fa0, fb2); MF(acc[1][2], fa1, fb2);
    MF(acc[2][2], fa2, fb2); MF(acc[3][2], fa3, fb2);
    MF(acc[0][3], fa0, fb3); MF(acc[1][3], fa1, fb3);
    MF(acc[2][3], fa2, fb3); MF(acc[3][3], fa3, fb3);
    __builtin_amdgcn_s_setprio(0);
    SB0(); BAR(); SB0();

    // ---- P1: buf0, a4-7 x b0-3
    ldA(fa0, 0, 4); ldA(fa1, 0, 5); ldA(fa2, 0, 6); ldA(fa3, 0, 7);
    if (pre) { stageB(0, 0, 2 * i + 2); stageB(0, 1, 2 * i + 2); }
    __builtin_amdgcn_s_setprio(1);
    MF(acc[4][0], fa0, fb0); MF(acc[5][0], fa1, fb0);
    MF(acc[6][0], fa2, fb0); MF(acc[7][0], fa3, fb0);
    MF(acc[4][1], fa0, fb1); MF(acc[5][1], fa1, fb1);
    MF(acc[6][1], fa2, fb1); MF(acc[7][1], fa3, fb1);
    MF(acc[4][2], fa0, fb2); MF(acc[5][2], fa1, fb2);
    MF(acc[6][2], fa2, fb2); MF(acc[7][2], fa3, fb2);
    MF(acc[4][3], fa0, fb3); MF(acc[5][3], fa1, fb3);
    MF(acc[6][3], fa2, fb3); MF(acc[7][3], fa3, fb3);
    __builtin_amdgcn_s_setprio(0);
    if (pre) { VMC(4); } else { VMC(0); }   // buf1 (tile t1) fully landed
    SB0(); BAR(); SB0();

    // ---- P2: buf1, a0-3 x b0-3
    ldA(fa0, 1, 0); ldA(fa1, 1, 1); ldA(fa2, 1, 2); ldA(fa3, 1, 3);
    ldB(fb0, 1, 0); ldB(fb1, 1, 1); ldB(fb2, 1, 2); ldB(fb3, 1, 3);
    if (pre) { stageA(0, 0, 2 * i + 2); stageA(0, 1, 2 * i + 2); }
    __builtin_amdgcn_s_setprio(1);
    MF(acc[0][0], fa0, fb0); MF(acc[1][0], fa1, fb0);
    MF(acc[2][0], fa2, fb0); MF(acc[3][0], fa3, fb0);
    MF(acc[0][1], fa0, fb1); MF(acc[1][1], fa1, fb1);
    MF(acc[2][1], fa2, fb1); MF(acc[3][1], fa3, fb1);
    MF(acc[0][2], fa0, fb2); MF(acc[1][2], fa1, fb2);
    MF(acc[2][2], fa2, fb2); MF(acc[3][2], fa3, fb2);
    MF(acc[0][3], fa0, fb3); MF(acc[1][3], fa1, fb3);
    MF(acc[2][3], fa2, fb3); MF(acc[3][3], fa3, fb3);
    __builtin_amdgcn_s_setprio(0);
    SB0(); BAR(); SB0();

    // ---- P3: buf1, a4-7 x b0-3
    ldA(fa0, 1, 4); ldA(fa1, 1, 5); ldA(fa2, 1, 6); ldA(fa3, 1, 7);
    if (pre) { stageB(1, 0, t1 + 2); stageB(1, 1, t1 + 2); }
    __builtin_amdgcn_s_setprio(1);
    MF(acc[4][0], fa0, fb0); MF(acc[5][0], fa1, fb0);
    MF(acc[6][0], fa2, fb0); MF(acc[7][0], fa3, fb0);
    MF(acc[4][1], fa0, fb1); MF(acc[5][1], fa1, fb1);
    MF(acc[6][1], fa2, fb1); MF(acc[7][1], fa3, fb1);
    MF(acc[4][2], fa0, fb2); MF(acc[5][2], fa1, fb2);
    MF(acc[6][2], fa2, fb2); MF(acc[7][2], fa3, fb2);
    MF(acc[4][3], fa0, fb3); MF(acc[5][3], fa1, fb3);
    MF(acc[6][3], fa2, fb3); MF(acc[7][3], fa3, fb3);
    __builtin_amdgcn_s_setprio(0);
    if (pre) { VMC(4); } else { VMC(0); }   // buf0 (tile t0+2) fully landed
    SB0(); BAR(); SB0();
  }

  __syncthreads();

  // ---- target-logit extraction (C layout: col=lane&15, row=q*4+reg)
#pragma unroll
  for (int ai = 0; ai < 8; ++ai) {
#pragma unroll
    for (int r = 0; r < 4; ++r) {
      int row_local = wr * 128 + ai * 16 + q * 4 + r;
      int c = stgt[row_local] - n0 - wc * 64;
      if ((unsigned)c < 64u && (c & 15) == lm) {
        int bj = c >> 4;
        float v = bj == 0 ? acc[ai][0][r]
                : bj == 1 ? acc[ai][1][r]
                : bj == 2 ? acc[ai][2][r]
                :           acc[ai][3][r];
        tl[m0 + row_local] = v * UNSCALE;
      }
    }
  }

  // ---- per-row (max, sumexp) over this wave's 64 columns
#pragma unroll
  for (int ai = 0; ai < 8; ++ai) {
#pragma unroll
    for (int r = 0; r < 4; ++r) {
      float v0 = acc[ai][0][r] * UNSCALE;
      float v1 = acc[ai][1][r] * UNSCALE;
      float v2 = acc[ai][2][r] * UNSCALE;
      float v3 = acc[ai][3][r] * UNSCALE;
      float mx = fmaxf(fmaxf(v0, v1), fmaxf(v2, v3));
#pragma unroll
      for (int off = 1; off < 16; off <<= 1) mx = fmaxf(mx, __shfl_xor(mx, off));
      float s = __expf(v0 - mx) + __expf(v1 - mx) + __expf(v2 - mx) + __expf(v3 - mx);
#pragma unroll
      for (int off = 1; off < 16; off <<= 1) s += __shfl_xor(s, off);
      if (lm == 0) {
        int row_local = wr * 128 + ai * 16 + q * 4 + r;
        red_m[wc][row_local] = mx;
        red_l[wc][row_local] = s;
      }
    }
  }
  __syncthreads();
  if (tid < BM) {
    float M = fmaxf(fmaxf(red_m[0][tid], red_m[1][tid]),
                    fmaxf(red_m[2][tid], red_m[3][tid]));
    float L = red_l[0][tid] * __expf(red_m[0][tid] - M)
            + red_l[1][tid] * __expf(red_m[1][tid] - M)
            + red_l[2][tid] * __expf(red_m[2][tid] - M)
            + red_l[3][tid] * __expf(red_m[3][tid] - M);
    long idx = (long)nt * BT + (m0 + tid);
    pm[idx] = M;
    pl[idx] = L;
  }
}

// -------------------------------------------- combine partials, wave per row
__global__ __launch_bounds__(256)
void row_lse_kernel(const float* __restrict__ pm, const float* __restrict__ pl,
                    const float* __restrict__ tl, const int* __restrict__ tgt,
                    float* __restrict__ rl) {
  int row  = blockIdx.x * 4 + (threadIdx.x >> 6);
  int lane = threadIdx.x & 63;
  float M = -__builtin_inff();
  float L = 0.f;
  for (int t = lane; t < NTILES; t += 64) {
    float m2 = pm[(long)t * BT + row];
    float l2 = pl[(long)t * BT + row];
    float Mn = fmaxf(M, m2);
    L = L * __expf(M - Mn) + l2 * __expf(m2 - Mn);
    M = Mn;
  }
#pragma unroll
  for (int off = 1; off < 64; off <<= 1) {
    float m2 = __shfl_xor(M, off);
    float l2 = __shfl_xor(L, off);
    float Mn = fmaxf(M, m2);
    L = L * __expf(M - Mn) + l2 * __expf(m2 - Mn);
    M = Mn;
  }
  if (lane == 0) {
    float lse = M + logf(L);
    int t = tgt[row];
    rl[row] = (t != IGNORE_INDEX) ? (lse - tl[row]) : 0.f;
  }
}

// ------------------------------------------------------------- final reduce
__global__ __launch_bounds__(256)
void final_kernel(const float* __restrict__ rl, const int* __restrict__ tgt,
                  float* __restrict__ out) {
  __shared__ float ss[4];
  __shared__ float sc[4];
  float s = 0.f, c = 0.f;
  for (int r = threadIdx.x; r < BT; r += 256) {
    s += rl[r];
    c += (tgt[r] != IGNORE_INDEX) ? 1.f : 0.f;
  }
#pragma unroll
  for (int off = 32; off > 0; off >>= 1) {
    s += __shfl_xor(s, off);
    c += __shfl_xor(c, off);
  }
  int w = threadIdx.x >> 6;
  if ((threadIdx.x & 63) == 0) { ss[w] = s; sc[w] = c; }
  __syncthreads();
  if (threadIdx.x == 0) {
    float S = ss[0] + ss[1] + ss[2] + ss[3];
    float C = sc[0] + sc[1] + sc[2] + sc[3];
    out[0] = S / fmaxf(C, 1.f);
  }
}

extern "C" void kernel_launch(void* const* d_in, const int* in_sizes, int n_in,
                              void* d_out, int out_size, void* d_ws, size_t ws_size,
                              hipStream_t stream) {
  const float* hs  = (const float*)d_in[0];   // hidden_states [BT][H] fp32
  const float* wt  = (const float*)d_in[1];   // weight [V][H] fp32
  const int*   tgt = (const int*)d_in[2];     // targets [BT]
  float*       out = (float*)d_out;

  char* ws = (char*)d_ws;
  size_t off = 0;
  auto alloc = [&](size_t bytes) -> void* {
    void* p = ws + off;
    off += (bytes + 255) & ~(size_t)255;
    return p;
  };
  unsigned char* wf8 = (unsigned char*)alloc((size_t)V * H);        // 65.5 MB packed
  unsigned char* hf8 = (unsigned char*)alloc((size_t)BT * H);       // 8.4 MB packed
  float* pm = (float*)alloc((size_t)NTILES * BT * 4);               // 2.0 MB
  float* pl = (float*)alloc((size_t)NTILES * BT * 4);               // 2.0 MB
  float* tl = (float*)alloc((size_t)BT * 4);
  float* rl = (float*)alloc((size_t)BT * 4);
  (void)ws_size; (void)in_sizes; (void)n_in; (void)out_size;

  // pack tasks: one wave per (16-row group, K-tile)
  cvt_pack_kernel<<<(V / 16) * KT / 4, 256, 0, stream>>>(wt, wf8, (V / 16) * KT);
  cvt_pack_kernel<<<(BT / 16) * KT / 4, 256, 0, stream>>>(hs, hf8, (BT / 16) * KT);

  gemm_lse_kernel<<<NWG, 512, 0, stream>>>(hf8, wf8, tgt, pm, pl, tl);

  row_lse_kernel<<<BT / 4, 256, 0, stream>>>(pm, pl, tl, tgt, rl);
  final_kernel<<<1, 256, 0, stream>>>(rl, tgt, out);
}